// Round 9
// baseline (111.603 us; speedup 1.0000x reference)
//
#include <hip/hip_runtime.h>
#include <hip/hip_bf16.h>

// GAT layer, N=8192, IN_F=256, OUT_F=64.
// k1 gat_pre : h = input@W; f1=(h@a1)*log2e, f2=(h@a2)*log2e; h packed bf16.
// k2 gat_main: grid (512 x 2 halves) x 256 thr, 4 blocks/CU resident.
//   PHASE 1: each wave streams its 4 adj row-halves sequentially (16KB/row,
//     2KB chunks) with NON-TEMPORAL loads (nt: no L2/L3 allocation — adj is
//     read-once) and bit-packs adj>0 into LDS bits[16][528].
//   PHASE 2: 32 K-steps/wave from LDS bits + LDS f2-half + L2-resident packed
//     hp; p = exp2(lrelu(f1'+f2')-shift'), shift'=lrelu(f1'+Fmax') (monotone
//     lrelu => arg<=0, shift shared across halves so partials combine
//     exactly); 4 MFMAs/step; partial num/den -> ws.
// k3 gat_fin : combine 2 half-partials, normalize, ELU.

using short8 = __attribute__((ext_vector_type(8))) short;
using f32x4  = __attribute__((ext_vector_type(4))) float;
using i32x4  = __attribute__((ext_vector_type(4))) int;   // NT-loadable vec

#define NN     8192
#define INF_   256
#define OUTF   64
#define LR_A   0.2f
#define LOG2E  1.4426950408889634f
#define ROWS   16
#define HCOLS  4096    // columns per half
#define BPAD   528     // bits row pitch (512 data + 16 pad)

__device__ __forceinline__ unsigned short f2bf_rne(float x) {
  unsigned int u = __float_as_uint(x);
  u += 0x7FFFu + ((u >> 16) & 1u);
  return (unsigned short)(u >> 16);
}

// ---------------- kernel 1: h (packed bf16), f1', f2' ----------------
__global__ __launch_bounds__(256) void gat_pre(
    const float* __restrict__ input, const float* __restrict__ W,
    const float* __restrict__ a, unsigned short* __restrict__ hp,
    float* __restrict__ f1, float* __restrict__ f2) {
  __shared__ float WT[OUTF][260];
  int tid = threadIdx.x;
  for (int idx = tid; idx < INF_ * OUTF; idx += 256) {
    int c = idx >> 6, f = idx & 63;
    WT[f][c] = W[idx];
  }
  __syncthreads();
  int w = tid >> 6, l = tid & 63;               // lane = output feature
  int i0 = blockIdx.x * 16 + w * 4;
  const float4* r0 = (const float4*)(input + (long)(i0 + 0) * INF_);
  const float4* r1 = (const float4*)(input + (long)(i0 + 1) * INF_);
  const float4* r2 = (const float4*)(input + (long)(i0 + 2) * INF_);
  const float4* r3 = (const float4*)(input + (long)(i0 + 3) * INF_);
  float h0 = 0.f, h1 = 0.f, h2 = 0.f, h3 = 0.f;
#pragma unroll 4
  for (int c4 = 0; c4 < INF_ / 4; ++c4) {
    float4 wv = *(const float4*)&WT[l][c4 * 4];
    float4 v0 = r0[c4], v1 = r1[c4], v2 = r2[c4], v3 = r3[c4];
    h0 = fmaf(v0.x, wv.x, h0); h0 = fmaf(v0.y, wv.y, h0);
    h0 = fmaf(v0.z, wv.z, h0); h0 = fmaf(v0.w, wv.w, h0);
    h1 = fmaf(v1.x, wv.x, h1); h1 = fmaf(v1.y, wv.y, h1);
    h1 = fmaf(v1.z, wv.z, h1); h1 = fmaf(v1.w, wv.w, h1);
    h2 = fmaf(v2.x, wv.x, h2); h2 = fmaf(v2.y, wv.y, h2);
    h2 = fmaf(v2.z, wv.z, h2); h2 = fmaf(v2.w, wv.w, h2);
    h3 = fmaf(v3.x, wv.x, h3); h3 = fmaf(v3.y, wv.y, h3);
    h3 = fmaf(v3.z, wv.z, h3); h3 = fmaf(v3.w, wv.w, h3);
  }
  float a1k = a[l], a2k = a[OUTF + l];
  float hh[4] = {h0, h1, h2, h3};
#pragma unroll
  for (int r = 0; r < 4; ++r) {
    int i = i0 + r;
    float t1 = hh[r] * a1k, t2 = hh[r] * a2k;
#pragma unroll
    for (int off = 32; off; off >>= 1) {
      t1 += __shfl_xor(t1, off);
      t2 += __shfl_xor(t2, off);
    }
    // packed: granule = (K32*4 + nb)*64 + g_i*16 + (feat&15), elem = i&7
    int gran = (((i >> 5) * 4) + (l >> 4)) * 64 + ((i >> 3) & 3) * 16 + (l & 15);
    hp[(long)gran * 8 + (i & 7)] = f2bf_rne(hh[r]);
    if (l == 0) { f1[i] = t1 * LOG2E; f2[i] = t2 * LOG2E; }
  }
}

// ---------------- kernel 2: stream+bitpack, then fused attention ------------
__global__ __launch_bounds__(256, 4) void gat_main(
    const int* __restrict__ adj, const unsigned short* __restrict__ hp,
    const float* __restrict__ f1, const float* __restrict__ f2,
    float* __restrict__ numP, float* __restrict__ denP) {
  __shared__ __align__(16) unsigned char bitsL[ROWS * BPAD];  // 8.45 KB
  __shared__ __align__(16) float f2s[HCOLS];                  // 16 KB (own half)
  __shared__ float ssum[4][ROWS];
  __shared__ float f1s[ROWS], shifts[ROWS], red[4];
  int tid = threadIdx.x;
  int w = tid >> 6, l = tid & 63;
  int i0 = blockIdx.x * ROWS;
  int ch = blockIdx.y;                          // column half 0..1

  // ---- prologue: global max of f2' (full scan), own half -> LDS ----
  float fm = -1e30f;
  for (int jj = tid * 4; jj < NN; jj += 1024) {
    float4 v = *(const float4*)(f2 + jj);
    fm = fmaxf(fm, fmaxf(fmaxf(v.x, v.y), fmaxf(v.z, v.w)));
  }
  for (int jj = tid * 4; jj < HCOLS; jj += 1024)
    *(float4*)&f2s[jj] = *(const float4*)(f2 + ch * HCOLS + jj);
#pragma unroll
  for (int off = 32; off; off >>= 1) fm = fmaxf(fm, __shfl_xor(fm, off));
  if (l == 0) red[w] = fm;
  __syncthreads();
  if (tid == 0) red[0] = fmaxf(fmaxf(red[0], red[1]), fmaxf(red[2], red[3]));
  __syncthreads();
  float Fmax = red[0];
  if (tid < ROWS) {
    float v = f1[i0 + tid];
    f1s[tid] = v;
    float s = v + Fmax;
    shifts[tid] = fmaxf(s, LR_A * s);           // lrelu(f1'+Fmax') >= row max
  }

  // ---- PHASE 1: stream own 4 row-halves sequentially (NT), bit-pack ----
  // lane l covers ints [l*8, l*8+8) of each 2KB chunk; 8 chunks per row-half.
#pragma unroll
  for (int r = 0; r < 4; ++r) {
    int rr = w * 4 + r;
    const i32x4* rowp = (const i32x4*)(adj + (long)(i0 + rr) * NN + ch * HCOLS)
                        + l * 2;
    unsigned char* brow = bitsL + rr * BPAD + l;
#pragma unroll
    for (int c = 0; c < 8; ++c) {
      i32x4 a = __builtin_nontemporal_load(rowp + c * 128);
      i32x4 b = __builtin_nontemporal_load(rowp + c * 128 + 1);
      unsigned bt = (a[0] > 0) | ((a[1] > 0) << 1) | ((a[2] > 0) << 2) |
                    ((a[3] > 0) << 3) | ((b[0] > 0) << 4) | ((b[1] > 0) << 5) |
                    ((b[2] > 0) << 6) | ((b[3] > 0) << 7);
      brow[c * 64] = (unsigned char)bt;
    }
  }
  __syncthreads();                              // bits + f2s + shifts ready

  // ---- PHASE 2: 32 K-steps per wave, all operands LDS/L2 ----
  int q = l & 15, g = l >> 4;                   // A-frag: row=q, k-group=g
  float f1r = f1s[q], sh = shifts[q];
  float u1 = f1r - sh, u2 = LR_A * f1r - sh;    // arg = max(u1+f2j, u2+0.2*f2j)
  f32x4 acc0 = {0.f, 0.f, 0.f, 0.f}, acc1 = acc0, acc2 = acc0, acc3 = acc0;
  float srow = 0.f;

  const unsigned char* bq = bitsL + q * BPAD + w * 128 + g;
  const float* f2w = f2s + w * 1024 + g * 8;
  const unsigned short* hpw = hp + (long)(ch * 128 + w * 32) * 2048 + l * 8;

  short8 hA[4], hB[4];
  auto load_hp = [&](short8* d, int t) {
    const unsigned short* p = hpw + (long)t * 2048;
    d[0] = *(const short8*)(p);
    d[1] = *(const short8*)(p + 512);
    d[2] = *(const short8*)(p + 1024);
    d[3] = *(const short8*)(p + 1536);
  };
  auto compute = [&](int t, const short8* H) {
    unsigned bt = bq[t * 4];                    // 8 mask bits for this lane
    const float* fb = f2w + t * 32;
    float4 F0 = *(const float4*)fb, F1 = *(const float4*)(fb + 4);
    float fa[8] = {F0.x, F0.y, F0.z, F0.w, F1.x, F1.y, F1.z, F1.w};
    union { short8 v; unsigned short u[8]; } pa;
    float ps = 0.f;
#pragma unroll
    for (int e = 0; e < 8; ++e) {
      float arg = fmaxf(u1 + fa[e], fmaf(LR_A, fa[e], u2));
      float pe = (bt & (1u << e)) ? exp2f(arg) : 0.f;
      ps += pe;
      pa.u[e] = f2bf_rne(pe);
    }
    srow += ps;
    acc0 = __builtin_amdgcn_mfma_f32_16x16x32_bf16(pa.v, H[0], acc0, 0, 0, 0);
    acc1 = __builtin_amdgcn_mfma_f32_16x16x32_bf16(pa.v, H[1], acc1, 0, 0, 0);
    acc2 = __builtin_amdgcn_mfma_f32_16x16x32_bf16(pa.v, H[2], acc2, 0, 0, 0);
    acc3 = __builtin_amdgcn_mfma_f32_16x16x32_bf16(pa.v, H[3], acc3, 0, 0, 0);
  };

  load_hp(hA, 0);
  for (int tt = 0; tt < 32; tt += 2) {
    load_hp(hB, tt + 1);
    compute(tt, hA);
    if (tt + 2 < 32) load_hp(hA, tt + 2);
    compute(tt + 1, hB);
  }

  // row sums: combine the 4 k-groups (lanes q, q+16, q+32, q+48)
  srow += __shfl_xor(srow, 16);
  srow += __shfl_xor(srow, 32);

  __syncthreads();                              // f2s dead; reuse as accs
  if (l < ROWS) ssum[w][l] = srow;
  float* accs = f2s;                            // [4][16][64] = 16 KB exactly
#pragma unroll
  for (int r = 0; r < 4; ++r) {
    accs[(w * ROWS + g * 4 + r) * OUTF + 0 * 16 + q] = acc0[r];
    accs[(w * ROWS + g * 4 + r) * OUTF + 1 * 16 + q] = acc1[r];
    accs[(w * ROWS + g * 4 + r) * OUTF + 2 * 16 + q] = acc2[r];
    accs[(w * ROWS + g * 4 + r) * OUTF + 3 * 16 + q] = acc3[r];
  }
  __syncthreads();

  // combine 4 waves; write this half's partial num/den
  for (int idx = tid; idx < ROWS * OUTF; idx += 256) {
    int m = idx >> 6, n = idx & 63;
    float num = 0.f, den = 0.f;
#pragma unroll
    for (int ww = 0; ww < 4; ++ww) {
      num += accs[(ww * ROWS + m) * OUTF + n];
      den += ssum[ww][m];
    }
    numP[((long)ch * NN + i0 + m) * OUTF + n] = num;
    if (n == 0) denP[(long)ch * NN + i0 + m] = den;
  }
}

// ---------------- kernel 3: combine halves, normalize, ELU ----------------
__global__ __launch_bounds__(256) void gat_fin(
    const float* __restrict__ numP, const float* __restrict__ denP,
    float* __restrict__ out) {
  int gid = blockIdx.x * 256 + threadIdx.x;     // [0, 8192*64)
  int row = gid >> 6;
  float num = numP[gid] + numP[(long)NN * OUTF + gid];
  float den = denP[row] + denP[NN + row];
  float v = num / den;
  out[gid] = v > 0.f ? v : expm1f(v);
}

extern "C" void kernel_launch(void* const* d_in, const int* in_sizes, int n_in,
                              void* d_out, int out_size, void* d_ws, size_t ws_size,
                              hipStream_t stream) {
  const float* input = (const float*)d_in[0];
  const int*   adj   = (const int*)d_in[1];
  const float* W     = (const float*)d_in[2];
  const float* a     = (const float*)d_in[3];
  float* out = (float*)d_out;
  char* ws = (char*)d_ws;
  unsigned short* hp = (unsigned short*)ws;             // 1 MB packed bf16 h
  float* f1   = (float*)(ws + (1 << 20));               // 32 KB (log2e-scaled)
  float* f2   = (float*)(ws + (1 << 20) + (32 << 10));  // 32 KB (log2e-scaled)
  float* numP = (float*)(ws + (1 << 20) + (64 << 10));  // 4 MB [2][8192][64]
  float* denP = (float*)(ws + (1 << 20) + (64 << 10) + (4 << 20)); // 64 KB
  (void)in_sizes; (void)n_in; (void)out_size; (void)ws_size;

  gat_pre<<<512, 256, 0, stream>>>(input, W, a, hp, f1, f2);
  gat_main<<<dim3(512, 2), 256, 0, stream>>>(adj, hp, f1, f2, numP, denP);
  gat_fin<<<NN * OUTF / 256, 256, 0, stream>>>(numP, denP, out);
}

// Round 10
// 105.742 us; speedup vs baseline: 1.0554x; 1.0554x over previous
//
#include <hip/hip_runtime.h>
#include <hip/hip_bf16.h>

// GAT layer, N=8192, IN_F=256, OUT_F=64.  [R7 config — best measured: 107.0 µs]
// k1 gat_pre : h = input@W; f1=(h@a1)*log2e, f2=(h@a2)*log2e; h packed bf16.
// k2 gat_main: 512 blocks x 256 thr; block owns 16 rows x ALL 8192 cols.
//   PHASE 1 (stream): each wave reads its 4 adj rows FULLY SEQUENTIALLY
//     (32KB/row, 2KB chunks) and bit-packs adj>0 into LDS bits[16][1040].
//     No NT (L3 absorbs ~40% of adj re-traffic — measured faster than NT).
//   PHASE 2 (compute): 64 K-steps/wave from LDS bits + LDS f2 + L2-resident
//     packed hp; p = exp2(lrelu(f1'+f2')-shift'), shift'=lrelu(f1'+Fmax')
//     (monotone lrelu => arg<=0, no online rescale); 4 MFMAs/step; direct
//     out write (no partials, no third kernel).
// Ceiling note: adj read (268 MB, irreducible) runs at the measured per-CU
// read-concurrency cap (~2.9 TB/s chip-wide); 8 schedule families all
// converge here. This config sits within ~5-7% of that structural floor.

using short8 = __attribute__((ext_vector_type(8))) short;
using f32x4  = __attribute__((ext_vector_type(4))) float;

#define NN     8192
#define INF_   256
#define OUTF   64
#define LR_A   0.2f
#define LOG2E  1.4426950408889634f
#define ROWS   16
#define BPAD   1040   // bits row pitch: 16B-aligned; bank drift 4/row => worst 2-way (free)

__device__ __forceinline__ unsigned short f2bf_rne(float x) {
  unsigned int u = __float_as_uint(x);
  u += 0x7FFFu + ((u >> 16) & 1u);
  return (unsigned short)(u >> 16);
}

// ---------------- kernel 1: h (packed bf16), f1', f2' ----------------
__global__ __launch_bounds__(256) void gat_pre(
    const float* __restrict__ input, const float* __restrict__ W,
    const float* __restrict__ a, unsigned short* __restrict__ hp,
    float* __restrict__ f1, float* __restrict__ f2) {
  __shared__ float WT[OUTF][260];
  int tid = threadIdx.x;
  for (int idx = tid; idx < INF_ * OUTF; idx += 256) {
    int c = idx >> 6, f = idx & 63;
    WT[f][c] = W[idx];
  }
  __syncthreads();
  int w = tid >> 6, l = tid & 63;               // lane = output feature
  int i0 = blockIdx.x * 16 + w * 4;
  const float4* r0 = (const float4*)(input + (long)(i0 + 0) * INF_);
  const float4* r1 = (const float4*)(input + (long)(i0 + 1) * INF_);
  const float4* r2 = (const float4*)(input + (long)(i0 + 2) * INF_);
  const float4* r3 = (const float4*)(input + (long)(i0 + 3) * INF_);
  float h0 = 0.f, h1 = 0.f, h2 = 0.f, h3 = 0.f;
#pragma unroll 4
  for (int c4 = 0; c4 < INF_ / 4; ++c4) {
    float4 wv = *(const float4*)&WT[l][c4 * 4];
    float4 v0 = r0[c4], v1 = r1[c4], v2 = r2[c4], v3 = r3[c4];
    h0 = fmaf(v0.x, wv.x, h0); h0 = fmaf(v0.y, wv.y, h0);
    h0 = fmaf(v0.z, wv.z, h0); h0 = fmaf(v0.w, wv.w, h0);
    h1 = fmaf(v1.x, wv.x, h1); h1 = fmaf(v1.y, wv.y, h1);
    h1 = fmaf(v1.z, wv.z, h1); h1 = fmaf(v1.w, wv.w, h1);
    h2 = fmaf(v2.x, wv.x, h2); h2 = fmaf(v2.y, wv.y, h2);
    h2 = fmaf(v2.z, wv.z, h2); h2 = fmaf(v2.w, wv.w, h2);
    h3 = fmaf(v3.x, wv.x, h3); h3 = fmaf(v3.y, wv.y, h3);
    h3 = fmaf(v3.z, wv.z, h3); h3 = fmaf(v3.w, wv.w, h3);
  }
  float a1k = a[l], a2k = a[OUTF + l];
  float hh[4] = {h0, h1, h2, h3};
#pragma unroll
  for (int r = 0; r < 4; ++r) {
    int i = i0 + r;
    float t1 = hh[r] * a1k, t2 = hh[r] * a2k;
#pragma unroll
    for (int off = 32; off; off >>= 1) {
      t1 += __shfl_xor(t1, off);
      t2 += __shfl_xor(t2, off);
    }
    // packed: granule = (K32*4 + nb)*64 + g_i*16 + (feat&15), elem = i&7
    int gran = (((i >> 5) * 4) + (l >> 4)) * 64 + ((i >> 3) & 3) * 16 + (l & 15);
    hp[(long)gran * 8 + (i & 7)] = f2bf_rne(hh[r]);
    if (l == 0) { f1[i] = t1 * LOG2E; f2[i] = t2 * LOG2E; }
  }
}

// ---------------- kernel 2: stream+bitpack, then fused attention ------------
__global__ __launch_bounds__(256, 3) void gat_main(
    const int* __restrict__ adj, const unsigned short* __restrict__ hp,
    const float* __restrict__ f1, const float* __restrict__ f2,
    float* __restrict__ out) {
  __shared__ __align__(16) unsigned char bitsL[ROWS * BPAD];  // 16.6 KB
  __shared__ float f2s[NN];                                   // 32 KB
  __shared__ float ssum[4][ROWS];
  __shared__ float f1s[ROWS], shifts[ROWS], red[4];
  int tid = threadIdx.x;
  int w = tid >> 6, l = tid & 63;
  int i0 = blockIdx.x * ROWS;

  // ---- prologue: f2' -> LDS, global max of f2', per-row shifts ----
  float fm = -1e30f;
  for (int jj = tid * 4; jj < NN; jj += 1024) {
    float4 v = *(const float4*)(f2 + jj);
    *(float4*)&f2s[jj] = v;
    fm = fmaxf(fm, fmaxf(fmaxf(v.x, v.y), fmaxf(v.z, v.w)));
  }
#pragma unroll
  for (int off = 32; off; off >>= 1) fm = fmaxf(fm, __shfl_xor(fm, off));
  if (l == 0) red[w] = fm;
  __syncthreads();
  if (tid == 0) red[0] = fmaxf(fmaxf(red[0], red[1]), fmaxf(red[2], red[3]));
  __syncthreads();
  float Fmax = red[0];
  if (tid < ROWS) {
    float v = f1[i0 + tid];
    f1s[tid] = v;
    float s = v + Fmax;
    shifts[tid] = fmaxf(s, LR_A * s);           // lrelu(f1'+Fmax') >= row max
  }

  // ---- PHASE 1: stream own 4 rows sequentially, bit-pack into LDS ----
  // lane l covers ints [l*8, l*8+8) of each 2KB chunk (2 x int4, 32B);
  // row = 16 chunks back-to-back -> long sequential DRAM runs per row.
#pragma unroll
  for (int r = 0; r < 4; ++r) {
    int rr = w * 4 + r;
    const int4* rowp = (const int4*)(adj + (long)(i0 + rr) * NN) + l * 2;
    unsigned char* brow = bitsL + rr * BPAD + l;
#pragma unroll 4
    for (int c = 0; c < 16; ++c) {
      int4 a = rowp[c * 128], b = rowp[c * 128 + 1];
      unsigned bt = (a.x > 0) | ((a.y > 0) << 1) | ((a.z > 0) << 2) |
                    ((a.w > 0) << 3) | ((b.x > 0) << 4) | ((b.y > 0) << 5) |
                    ((b.z > 0) << 6) | ((b.w > 0) << 7);
      brow[c * 64] = (unsigned char)bt;
    }
  }
  __syncthreads();                              // bits + f2s + shifts ready

  // ---- PHASE 2: 64 K-steps per wave, all operands LDS/L2 ----
  int q = l & 15, g = l >> 4;                   // A-frag: row=q, k-group=g
  float f1r = f1s[q], sh = shifts[q];
  float u1 = f1r - sh, u2 = LR_A * f1r - sh;    // arg = max(u1+f2j, u2+0.2*f2j)
  f32x4 acc0 = {0.f, 0.f, 0.f, 0.f}, acc1 = acc0, acc2 = acc0, acc3 = acc0;
  float srow = 0.f;

  const unsigned char* bq = bitsL + q * BPAD + w * 256 + g;
  const float* f2w = f2s + w * 2048 + g * 8;
  const unsigned short* hpw = hp + (long)w * 64 * 2048 + l * 8;

  short8 hA[4], hB[4];
  auto load_hp = [&](short8* d, int t) {
    const unsigned short* p = hpw + (long)t * 2048;
    d[0] = *(const short8*)(p);
    d[1] = *(const short8*)(p + 512);
    d[2] = *(const short8*)(p + 1024);
    d[3] = *(const short8*)(p + 1536);
  };
  auto compute = [&](int t, const short8* H) {
    unsigned bt = bq[t * 4];                    // 8 mask bits for this lane
    const float* fb = f2w + t * 32;
    float4 F0 = *(const float4*)fb, F1 = *(const float4*)(fb + 4);
    float fa[8] = {F0.x, F0.y, F0.z, F0.w, F1.x, F1.y, F1.z, F1.w};
    union { short8 v; unsigned short u[8]; } pa;
    float ps = 0.f;
#pragma unroll
    for (int e = 0; e < 8; ++e) {
      float arg = fmaxf(u1 + fa[e], fmaf(LR_A, fa[e], u2));
      float pe = (bt & (1u << e)) ? exp2f(arg) : 0.f;
      ps += pe;
      pa.u[e] = f2bf_rne(pe);
    }
    srow += ps;
    acc0 = __builtin_amdgcn_mfma_f32_16x16x32_bf16(pa.v, H[0], acc0, 0, 0, 0);
    acc1 = __builtin_amdgcn_mfma_f32_16x16x32_bf16(pa.v, H[1], acc1, 0, 0, 0);
    acc2 = __builtin_amdgcn_mfma_f32_16x16x32_bf16(pa.v, H[2], acc2, 0, 0, 0);
    acc3 = __builtin_amdgcn_mfma_f32_16x16x32_bf16(pa.v, H[3], acc3, 0, 0, 0);
  };

  load_hp(hA, 0);
  for (int tt = 0; tt < 64; tt += 2) {
    load_hp(hB, tt + 1);
    compute(tt, hA);
    if (tt + 2 < 64) load_hp(hA, tt + 2);
    compute(tt + 1, hB);
  }

  // row sums: combine the 4 k-groups (lanes q, q+16, q+32, q+48)
  srow += __shfl_xor(srow, 16);
  srow += __shfl_xor(srow, 32);

  __syncthreads();                              // bits dead; reuse as accs
  if (l < ROWS) ssum[w][l] = srow;
  float* accs = (float*)bitsL;                  // [4][16][64] = 16 KB
#pragma unroll
  for (int r = 0; r < 4; ++r) {
    accs[(w * ROWS + g * 4 + r) * OUTF + 0 * 16 + q] = acc0[r];
    accs[(w * ROWS + g * 4 + r) * OUTF + 1 * 16 + q] = acc1[r];
    accs[(w * ROWS + g * 4 + r) * OUTF + 2 * 16 + q] = acc2[r];
    accs[(w * ROWS + g * 4 + r) * OUTF + 3 * 16 + q] = acc3[r];
  }
  __syncthreads();

  // combine 4 waves, normalize, ELU, write final output
  for (int idx = tid; idx < ROWS * OUTF; idx += 256) {
    int m = idx >> 6, n = idx & 63;
    float num = 0.f, den = 0.f;
#pragma unroll
    for (int ww = 0; ww < 4; ++ww) {
      num += accs[(ww * ROWS + m) * OUTF + n];
      den += ssum[ww][m];
    }
    float v = num / den;
    out[(long)(i0 + m) * OUTF + n] = v > 0.f ? v : expm1f(v);
  }
}

extern "C" void kernel_launch(void* const* d_in, const int* in_sizes, int n_in,
                              void* d_out, int out_size, void* d_ws, size_t ws_size,
                              hipStream_t stream) {
  const float* input = (const float*)d_in[0];
  const int*   adj   = (const int*)d_in[1];
  const float* W     = (const float*)d_in[2];
  const float* a     = (const float*)d_in[3];
  float* out = (float*)d_out;
  char* ws = (char*)d_ws;
  unsigned short* hp = (unsigned short*)ws;             // 1 MB packed bf16 h
  float* f1 = (float*)(ws + (1 << 20));                 // 32 KB (log2e-scaled)
  float* f2 = (float*)(ws + (1 << 20) + (32 << 10));    // 32 KB (log2e-scaled)
  (void)in_sizes; (void)n_in; (void)out_size; (void)ws_size;

  gat_pre<<<512, 256, 0, stream>>>(input, W, a, hp, f1, f2);
  gat_main<<<512, 256, 0, stream>>>(adj, hp, f1, f2, out);
}